// Round 8
// baseline (244.525 us; speedup 1.0000x reference)
//
#include <hip/hip_runtime.h>
#include <math.h>

#define T_SEQ 34
#define NTOK 14
#define NE (T_SEQ * NTOK) // 476

// ---- workspace table layout (float4 units) ----
#define OFF_RT   0              // 476 f4 : (rn, h0, h1, 0) per (s,tok)
#define OFF_POS  476            // 34 f4  : (px,py,pz,0) per t
#define OFF_MISC 510            // 56 f4  : misc floats (see MI_*)
#define NF4_SHARED 566          // copied to LDS by main kernel
#define OFF_DTAB 566            // 476 rows * 9 f4 (36 floats, 34 used + 2 pad)
#define DROW_F 36
#define NF4_TOTAL (NF4_SHARED + NE * (DROW_F/4))
#define WS_NEED ((size_t)NF4_TOTAL * 16)
// misc float indices (relative to misc base)
#define MI_TE    0    // 28
#define MI_WST   32   // 112 : WsT[v*8+d]
#define MI_PM    144  // 10
#define MI_LN2   160  // 5
#define MI_LNF   168  // 5
#define MI_FC1W  176  // 10
#define MI_FC1B  186  // 2
#define MI_FC2W  192  // 10
#define MI_FC2B  208  // 5

// main kernel geometry
#define ROWS 15
#define BLK 256
#define NEL (ROWS * T_SEQ)   // 510
#define TRS 36               // toksR row stride (ints): 144B, 16B-aligned
#define AVS 17               // Av row stride

// ---------------- position helper ----------------
__device__ inline void pos_for_t(int t,
    float amp, float ph, float slp, float off, float pcs, float pci,
    const float* __restrict__ z_hi, const float* __restrict__ spec,
    float& px, float& py, float& pz)
{
    if (t == 33)      { px = 0.f;     py = 0.f;     pz = 0.f; }
    else if (t == 32) { px = z_hi[0]; py = z_hi[1]; pz = z_hi[2]; }
    else if (t == 10) { px = spec[0]; py = spec[1]; pz = spec[2]; }
    else if (t == 21) { px = spec[3]; py = spec[4]; pz = spec[5]; }
    else {
        int i = (t < 10) ? t : (t < 21 ? t - 11 : t - 22);
        float fi = (float)i;
        float ang = 0.62831853071795864769f * fi + ph;
        float mlt = 1.f + pci + pcs * fi;
        px = amp * cosf(ang) * mlt;
        py = amp * sinf(ang) * mlt;
        pz = (slp * fi + off) * mlt;
    }
}

// ---------------- setup kernel: build all tables in d_ws ----------------
__global__ __launch_bounds__(64) void setup_kernel(
    const float* __restrict__ tok_emb,
    const float* __restrict__ s_amp, const float* __restrict__ s_phase,
    const float* __restrict__ s_slope, const float* __restrict__ s_offset,
    const float* __restrict__ pc_slope, const float* __restrict__ pc_int,
    const float* __restrict__ z_hi, const float* __restrict__ spec,
    const float* __restrict__ q_w, const float* __restrict__ v_w,
    const float* __restrict__ out_A, const float* __restrict__ out_B,
    const float* __restrict__ q_phase,
    const float* __restrict__ ln1_w, const float* __restrict__ ln2_w,
    const float* __restrict__ lnf_w,
    const float* __restrict__ fc1_w, const float* __restrict__ fc1_b,
    const float* __restrict__ fc2_w, const float* __restrict__ fc2_b,
    const float* __restrict__ head_w,
    float4* __restrict__ ws)
{
    __shared__ float4 PWs[T_SEQ];   // (px*w2, py*w3, pz*w4, 0)
    __shared__ float4 Poss[T_SEQ];

    const int tid = threadIdx.x;
    const float amp = s_amp[0], ph = s_phase[0], slp = s_slope[0], off = s_offset[0];
    const float pcs = pc_slope[0], pci = pc_int[0];

    if (tid < T_SEQ) {
        float px, py, pz;
        pos_for_t(tid, amp, ph, slp, off, pcs, pci, z_hi, spec, px, py, pz);
        PWs[tid]  = make_float4(px * ln1_w[2], py * ln1_w[3], pz * ln1_w[4], 0.f);
        Poss[tid] = make_float4(px, py, pz, 0.f);
    }
    __syncthreads();

    const int q = blockIdx.x * 64 + tid;
    if (q < NE) {
        const int t = q / NTOK, tk = q - t * NTOK;
        const float cph = cosf(q_phase[0]), sph = sinf(q_phase[0]);
        const float cscale = 0.44721359549995793f * 1.4426950408889634f; // 1/sqrt(5)*log2e
        float4 P = Poss[t];
        float px = P.x, py = P.y, pz = P.z;
        float x0 = tok_emb[tk * 2], x1 = tok_emb[tk * 2 + 1];
        float ssum = x0*x0 + x1*x1 + px*px + py*py + pz*pz;
        float rn = rsqrtf(ssum * 0.2f + 1e-5f);
        float h0 = x0 * rn * ln1_w[0], h1 = x1 * rn * ln1_w[1];
        float h2 = px * rn * ln1_w[2], h3 = py * rn * ln1_w[3], h4 = pz * rn * ln1_w[4];
        float q0 = q_w[0]  * h2 + q_w[1]  * h3 + q_w[2]  * h4;
        float q1 = q_w[3]  * h2 + q_w[4]  * h3 + q_w[5]  * h4;
        float q2 = q_w[6]  * h2 + q_w[7]  * h3 + q_w[8]  * h4;
        float q3 = q_w[9]  * h2 + q_w[10] * h3 + q_w[11] * h4;
        float q4 = q_w[12] * h2 + q_w[13] * h3 + q_w[14] * h4;
        float r0 = q0 * cph - q1 * sph, r1 = q0 * sph + q1 * cph;
        float r2c = q2 * cph - q3 * sph, r3 = q2 * sph + q3 * cph;
        float c0 = (r0*q_w[0] + r1*q_w[3] + r2c*q_w[6] + r3*q_w[9]  + q4*q_w[12]) * cscale;
        float c1 = (r0*q_w[1] + r1*q_w[4] + r2c*q_w[7] + r3*q_w[10] + q4*q_w[13]) * cscale;
        float c2 = (r0*q_w[2] + r1*q_w[5] + r2c*q_w[8] + r3*q_w[11] + q4*q_w[14]) * cscale;

        ws[OFF_RT + q] = make_float4(rn, h0, h1, 0.f);
        if (tk == 0) ws[OFF_POS + t] = Poss[t];

        float* Drow = (float*)(ws + OFF_DTAB) + q * DROW_F;
        for (int s = 0; s < T_SEQ; ++s) {
            float4 pw = PWs[s];
            Drow[s] = fmaf(c0, pw.x, fmaf(c1, pw.y, c2 * pw.z));
        }
        Drow[34] = 0.f; Drow[35] = 0.f;
    }

    if (blockIdx.x == 0) {
        float* M = (float*)(ws + OFF_MISC);
        if (tid < 28) M[MI_TE + tid] = tok_emb[tid];
        for (int i = tid; i < 70; i += 64) { // WsT[v*8+d]
            int v = i / 5, d = i - v * 5;
            M[MI_WST + v * 8 + d] = head_w[d] * tok_emb[v * 2]
                                  + head_w[5 + d] * tok_emb[v * 2 + 1];
        }
        if (tid < 10) { // PM[j][c]
            int j = tid >> 1, c = tid & 1;
            float acc = 0.f;
            for (int i = 0; i < 5; ++i) {
                float m5 = out_A[i*2] * out_B[j] + out_A[i*2+1] * out_B[5 + j];
                acc += m5 * v_w[i*2 + c];
            }
            M[MI_PM + tid] = acc;
        }
        if (tid < 5)  { M[MI_LN2 + tid] = ln2_w[tid]; M[MI_LNF + tid] = lnf_w[tid];
                        M[MI_FC2B + tid] = fc2_b[tid]; }
        if (tid < 10) { M[MI_FC1W + tid] = fc1_w[tid]; M[MI_FC2W + tid] = fc2_w[tid]; }
        if (tid < 2)  { M[MI_FC1B + tid] = fc1_b[tid]; }
    }
}

// ---------------- main kernel ----------------
__global__ __launch_bounds__(BLK) void micro_main(
    const int* __restrict__ idx, const float4* __restrict__ ws,
    float* __restrict__ out, int N)
{
    __shared__ float4 TBLs[NF4_SHARED];     // Rt | Pos | Misc
    __shared__ float4 GmL[NEL];             // [s][r], stride ROWS: gathered (rn,h0,h1)
    __shared__ int    toksR[ROWS * TRS];    // row-major, 36-int stride
    __shared__ float2 Av[T_SEQ * AVS];

    const int tid = threadIdx.x;
    const int elemBase = blockIdx.x * NEL;

    for (int i = tid; i < NF4_SHARED; i += BLK) TBLs[i] = ws[i];
    for (int i = tid; i < NEL; i += BLK) {
        int g = elemBase + i;
        int v = (g < N) ? idx[g] : 0;
        int r = i / T_SEQ, s = i - r * T_SEQ;
        toksR[r * TRS + s] = v;
    }
    __syncthreads();

    // ---- Gm staging: ONE dependent gather per (s,r); kills the 17x-redundant
    //      tok->Rt chains that were the phase-1 critical path in rounds 3-6. ----
    for (int i = tid; i < NEL; i += BLK) {
        const int s = i / ROWS, r = i - s * ROWS;  // i = s*ROWS + r -> contiguous write
        const int tok = toksR[r * TRS + s];
        GmL[i] = TBLs[s * NTOK + tok];             // OFF_RT == 0
    }
    __syncthreads();

    const float* Dtab = (const float*)(ws + OFF_DTAB);

    // ---- phase 1: fully-unrolled attention, induction-addressed Gm stream ----
    if (tid < 17 * ROWS) {          // 255 threads
        const int p = tid / ROWS;   // 0..16  -> t1 = p
        const int r = tid - p * ROWS;
        const int t1 = p, t2 = 33 - p;

        const int tok1 = toksR[r * TRS + t1];
        const int tok2 = toksR[r * TRS + t2];
        const float4* D1 = (const float4*)(Dtab + (t1 * NTOK + tok1) * DROW_F);
        const float4* D2 = (const float4*)(Dtab + (t2 * NTOK + tok2) * DROW_F);

        float l1 = 0.f, a10 = 0.f, a11 = 0.f;
        float l2 = 0.f, a20 = 0.f, a21 = 0.f;

#pragma unroll
        for (int sb = 0; sb < 9; ++sb) {
            float4 d1 = make_float4(0.f, 0.f, 0.f, 0.f);
            if (sb <= 4) d1 = D1[sb];                     // t1 range: s <= 16 only
            const float4 d2 = D2[sb];
#pragma unroll
            for (int k = 0; k < 4; ++k) {
                const int s = (sb << 2) + k;
                if (s >= T_SEQ) continue;
                const float4 g = GmL[s * ROWS + r];       // induction address, no chain
                if (s <= 16) {  // t1 <= 16
                    const float dk1 = (k == 0) ? d1.x : (k == 1) ? d1.y : (k == 2) ? d1.z : d1.w;
                    float pv1 = __builtin_amdgcn_exp2f(dk1 * g.x);
                    if (s > 0) pv1 = (s <= t1) ? pv1 : 0.f;
                    l1 += pv1; a10 = fmaf(pv1, g.y, a10); a11 = fmaf(pv1, g.z, a11);
                }
                {   // t2 >= 17: unconditional for s <= 17
                    const float dk2 = (k == 0) ? d2.x : (k == 1) ? d2.y : (k == 2) ? d2.z : d2.w;
                    float pv2 = __builtin_amdgcn_exp2f(dk2 * g.x);
                    if (s >= 18) pv2 = (s <= t2) ? pv2 : 0.f;
                    l2 += pv2; a20 = fmaf(pv2, g.y, a20); a21 = fmaf(pv2, g.z, a21);
                }
            }
        }
        const float il1 = __builtin_amdgcn_rcpf(l1);
        const float il2 = __builtin_amdgcn_rcpf(l2);
        Av[t1 * AVS + r] = make_float2(a10 * il1, a11 * il1);
        Av[t2 * AVS + r] = make_float2(a20 * il2, a21 * il2);
    }
    __syncthreads();

    // ---- phase 2: residual + FFN + final RMS + logits (coalesced writes) ----
    const float* M = (const float*)&TBLs[OFF_MISC];
    float zA[5], zB[5];
    int linA = elemBase + tid;
    int linB = elemBase + tid + BLK;
    bool va = (tid < NEL) && (linA < N);
    bool vb = (tid + BLK < NEL) && (linB < N);

    auto prep = [&](int e2, float* z) {
        int rr = e2 / T_SEQ;
        int t = e2 - rr * T_SEQ;
        int tok = toksR[rr * TRS + t];
        float2 a = Av[t * AVS + rr];
        float2 te = *(const float2*)&M[MI_TE + tok * 2];
        float4 P = TBLs[OFF_POS + t];

        float y[5];
        y[0] = te.x + M[MI_PM + 0] * a.x + M[MI_PM + 1] * a.y;
        y[1] = te.y + M[MI_PM + 2] * a.x + M[MI_PM + 3] * a.y;
        y[2] = P.x  + M[MI_PM + 4] * a.x + M[MI_PM + 5] * a.y;
        y[3] = P.y  + M[MI_PM + 6] * a.x + M[MI_PM + 7] * a.y;
        y[4] = P.z  + M[MI_PM + 8] * a.x + M[MI_PM + 9] * a.y;

        float s2 = y[0]*y[0] + y[1]*y[1] + y[2]*y[2] + y[3]*y[3] + y[4]*y[4];
        float r2 = rsqrtf(s2 * 0.2f + 1e-5f);
        float hh[5];
#pragma unroll
        for (int j = 0; j < 5; ++j) hh[j] = y[j] * r2 * M[MI_LN2 + j];

        float u0 = M[MI_FC1B + 0], u1 = M[MI_FC1B + 1];
#pragma unroll
        for (int j = 0; j < 5; ++j) { u0 += hh[j] * M[MI_FC1W + j]; u1 += hh[j] * M[MI_FC1W + 5 + j]; }
        float g0 = 0.5f * u0 * (1.f + erff(u0 * 0.70710678118654752f));
        float g1v = 0.5f * u1 * (1.f + erff(u1 * 0.70710678118654752f));

        float y2[5]; float s3 = 0.f;
#pragma unroll
        for (int j = 0; j < 5; ++j) {
            y2[j] = y[j] + g0 * M[MI_FC2W + j*2] + g1v * M[MI_FC2W + j*2 + 1] + M[MI_FC2B + j];
            s3 += y2[j] * y2[j];
        }
        float r3 = rsqrtf(s3 * 0.2f + 1e-5f);
#pragma unroll
        for (int j = 0; j < 5; ++j) z[j] = y2[j] * r3 * M[MI_LNF + j];
    };

    if (va) prep(tid, zA);
    if (vb) prep(tid + BLK, zB);

    float2* opA = (float2*)(out + (size_t)linA * 14);
    float2* opB = (float2*)(out + (size_t)linB * 14);
#pragma unroll
    for (int v = 0; v < 7; ++v) {
        float4 w0 = *(const float4*)&M[MI_WST + (2*v) * 8];
        float  w4 = M[MI_WST + (2*v) * 8 + 4];
        float4 u0 = *(const float4*)&M[MI_WST + (2*v+1) * 8];
        float  u4 = M[MI_WST + (2*v+1) * 8 + 4];
        if (va) {
            float rA = zA[0]*w0.x + zA[1]*w0.y + zA[2]*w0.z + zA[3]*w0.w + zA[4]*w4;
            float rB = zA[0]*u0.x + zA[1]*u0.y + zA[2]*u0.z + zA[3]*u0.w + zA[4]*u4;
            opA[v] = make_float2(rA, rB);
        }
        if (vb) {
            float rA = zB[0]*w0.x + zB[1]*w0.y + zB[2]*w0.z + zB[3]*w0.w + zB[4]*w4;
            float rB = zB[0]*u0.x + zB[1]*u0.y + zB[2]*u0.z + zB[3]*u0.w + zB[4]*u4;
            opB[v] = make_float2(rA, rB);
        }
    }
}

// ---------------- legacy fallback (round-3 kernel, verified) ----------------
#define L_ROWS 30
#define L_BLK 512
#define L_NEL (L_ROWS * T_SEQ)
#define L_AVS (L_ROWS + 1)
#define L_TTS (L_ROWS + 1)

__global__ __launch_bounds__(L_BLK, 4) void micro_fused_legacy(
    const int* __restrict__ idx,
    const float* __restrict__ tok_emb,
    const float* __restrict__ s_amp, const float* __restrict__ s_phase,
    const float* __restrict__ s_slope, const float* __restrict__ s_offset,
    const float* __restrict__ pc_slope, const float* __restrict__ pc_int,
    const float* __restrict__ z_hi, const float* __restrict__ spec,
    const float* __restrict__ q_w, const float* __restrict__ v_w,
    const float* __restrict__ out_A, const float* __restrict__ out_B,
    const float* __restrict__ q_phase,
    const float* __restrict__ ln1_w, const float* __restrict__ ln2_w,
    const float* __restrict__ lnf_w,
    const float* __restrict__ fc1_w, const float* __restrict__ fc1_b,
    const float* __restrict__ fc2_w, const float* __restrict__ fc2_b,
    const float* __restrict__ head_w,
    float* __restrict__ out, int N)
{
    __shared__ float4 H4[NE];
    __shared__ float  H1f[NE];
    __shared__ float4 C3[NE];
    __shared__ float2 Av[T_SEQ * L_AVS];
    __shared__ int    toksT[T_SEQ * L_TTS];
    alignas(16) __shared__ float PosT[T_SEQ * 3];
    alignas(16) __shared__ float TE[NTOK * 2];
    alignas(16) __shared__ float PMs[12];
    alignas(16) __shared__ float WsT[NTOK * 8];
    alignas(16) __shared__ float ln2s[8], lnfs[8], fc1ws[12], fc2ws[12], fc2bs[8];
    __shared__ float fc1bs[2];

    const int tid = threadIdx.x;
    const int elemBase = blockIdx.x * L_NEL;

    for (int i = tid; i < L_NEL; i += L_BLK) {
        int g = elemBase + i;
        int v = (g < N) ? idx[g] : 0;
        int r = i / T_SEQ, s = i - r * T_SEQ;
        toksT[s * L_TTS + r] = v;
    }
    if (tid < NE) {
        const float amp = s_amp[0], ph = s_phase[0], slp = s_slope[0], off = s_offset[0];
        const float pcs = pc_slope[0], pci = pc_int[0];
        const float cph = cosf(q_phase[0]), sph = sinf(q_phase[0]);
        const float cscale = 0.44721359549995793f * 1.4426950408889634f;
        const int e = tid;
        const int t = e / NTOK, tk = e - t * NTOK;
        float px, py, pz;
        pos_for_t(t, amp, ph, slp, off, pcs, pci, z_hi, spec, px, py, pz);
        if (tk == 0) { PosT[t*3] = px; PosT[t*3+1] = py; PosT[t*3+2] = pz; }
        float x0 = tok_emb[tk * 2], x1 = tok_emb[tk * 2 + 1];
        float ssum = x0*x0 + x1*x1 + px*px + py*py + pz*pz;
        float rn = rsqrtf(ssum * 0.2f + 1e-5f);
        float h0 = x0 * rn * ln1_w[0], h1 = x1 * rn * ln1_w[1];
        float h2 = px * rn * ln1_w[2], h3 = py * rn * ln1_w[3], h4 = pz * rn * ln1_w[4];
        float q0 = q_w[0]  * h2 + q_w[1]  * h3 + q_w[2]  * h4;
        float q1 = q_w[3]  * h2 + q_w[4]  * h3 + q_w[5]  * h4;
        float q2 = q_w[6]  * h2 + q_w[7]  * h3 + q_w[8]  * h4;
        float q3 = q_w[9]  * h2 + q_w[10] * h3 + q_w[11] * h4;
        float q4 = q_w[12] * h2 + q_w[13] * h3 + q_w[14] * h4;
        float r0 = q0 * cph - q1 * sph, r1 = q0 * sph + q1 * cph;
        float r2c = q2 * cph - q3 * sph, r3 = q2 * sph + q3 * cph;
        float c0 = (r0*q_w[0] + r1*q_w[3] + r2c*q_w[6] + r3*q_w[9]  + q4*q_w[12]) * cscale;
        float c1 = (r0*q_w[1] + r1*q_w[4] + r2c*q_w[7] + r3*q_w[10] + q4*q_w[13]) * cscale;
        float c2 = (r0*q_w[2] + r1*q_w[5] + r2c*q_w[8] + r3*q_w[11] + q4*q_w[14]) * cscale;
        H4[e] = make_float4(h2, h3, h4, h0);
        H1f[e] = h1;
        C3[e] = make_float4(c0, c1, c2, 0.f);
    }
    if (tid < 28) TE[tid] = tok_emb[tid];
    if (tid < 70) {
        int v = tid / 5, d = tid - v * 5;
        WsT[v * 8 + d] = head_w[d] * tok_emb[v * 2] + head_w[5 + d] * tok_emb[v * 2 + 1];
    }
    if (tid < 10) {
        int j = tid >> 1, c = tid & 1;
        float acc = 0.f;
        for (int i = 0; i < 5; ++i) {
            float m5 = out_A[i*2] * out_B[j] + out_A[i*2+1] * out_B[5 + j];
            acc += m5 * v_w[i*2 + c];
        }
        PMs[tid] = acc;
    }
    if (tid < 5)  { ln2s[tid] = ln2_w[tid]; lnfs[tid] = lnf_w[tid]; fc2bs[tid] = fc2_b[tid]; }
    if (tid < 10) { fc1ws[tid] = fc1_w[tid]; fc2ws[tid] = fc2_w[tid]; }
    if (tid < 2)  { fc1bs[tid] = fc1_b[tid]; }
    __syncthreads();

    auto attn = [&](int t, int rr) {
        int tokt = toksT[t * L_TTS + rr];
        float4 c3 = C3[t * NTOK + tokt];
        float l = 0.f, a0 = 0.f, a1 = 0.f;
#pragma unroll 2
        for (int s = 0; s <= t; ++s) {
            int tok = toksT[s * L_TTS + rr];
            int e = s * NTOK + tok;
            float4 h = H4[e];
            float h1v = H1f[e];
            float sc = fmaf(c3.x, h.x, fmaf(c3.y, h.y, c3.z * h.z));
            float p = __builtin_amdgcn_exp2f(sc);
            l += p;
            a0 = fmaf(p, h.w, a0);
            a1 = fmaf(p, h1v, a1);
        }
        float il = __builtin_amdgcn_rcpf(l);
        Av[t * L_AVS + rr] = make_float2(a0 * il, a1 * il);
    };
    if (tid < 17 * L_ROWS) {
        int p = tid / L_ROWS;
        int r = tid - p * L_ROWS;
        attn(p, r);
        attn(33 - p, r);
    }
    __syncthreads();

    float zA[5], zB[5];
    int linA = elemBase + tid;
    int linB = elemBase + tid + L_BLK;
    bool va = (tid < L_NEL) && (linA < N);
    bool vb = (tid + L_BLK < L_NEL) && (linB < N);

    auto prep = [&](int e2, float* z) {
        int rr = e2 / T_SEQ;
        int t = e2 - rr * T_SEQ;
        int tok = toksT[t * L_TTS + rr];
        float2 a = Av[t * L_AVS + rr];
        float xv0 = TE[tok * 2], xv1 = TE[tok * 2 + 1];
        float xv2 = PosT[t*3], xv3 = PosT[t*3+1], xv4 = PosT[t*3+2];
        float y[5];
#pragma unroll
        for (int j = 0; j < 5; ++j)
            y[j] = (j == 0 ? xv0 : j == 1 ? xv1 : j == 2 ? xv2 : j == 3 ? xv3 : xv4)
                 + PMs[j*2] * a.x + PMs[j*2+1] * a.y;
        float s2 = y[0]*y[0] + y[1]*y[1] + y[2]*y[2] + y[3]*y[3] + y[4]*y[4];
        float r2 = rsqrtf(s2 * 0.2f + 1e-5f);
        float hh[5];
#pragma unroll
        for (int j = 0; j < 5; ++j) hh[j] = y[j] * r2 * ln2s[j];
        float u0 = fc1bs[0], u1 = fc1bs[1];
#pragma unroll
        for (int j = 0; j < 5; ++j) { u0 += hh[j] * fc1ws[j]; u1 += hh[j] * fc1ws[5 + j]; }
        float g0 = 0.5f * u0 * (1.f + erff(u0 * 0.70710678118654752f));
        float g1v = 0.5f * u1 * (1.f + erff(u1 * 0.70710678118654752f));
        float y2[5]; float s3 = 0.f;
#pragma unroll
        for (int j = 0; j < 5; ++j) {
            y2[j] = y[j] + g0 * fc2ws[j * 2] + g1v * fc2ws[j * 2 + 1] + fc2bs[j];
            s3 += y2[j] * y2[j];
        }
        float r3 = rsqrtf(s3 * 0.2f + 1e-5f);
#pragma unroll
        for (int j = 0; j < 5; ++j) z[j] = y2[j] * r3 * lnfs[j];
    };

    if (va) prep(tid, zA);
    if (vb) prep(tid + L_BLK, zB);

    float2* opA = (float2*)(out + (size_t)linA * 14);
    float2* opB = (float2*)(out + (size_t)linB * 14);
#pragma unroll
    for (int v = 0; v < 7; ++v) {
        float4 w0 = *(const float4*)&WsT[(2*v) * 8];
        float  w4 = WsT[(2*v) * 8 + 4];
        float4 u0 = *(const float4*)&WsT[(2*v+1) * 8];
        float  u4 = WsT[(2*v+1) * 8 + 4];
        if (va) {
            float rA = zA[0]*w0.x + zA[1]*w0.y + zA[2]*w0.z + zA[3]*w0.w + zA[4]*w4;
            float rB = zA[0]*u0.x + zA[1]*u0.y + zA[2]*u0.z + zA[3]*u0.w + zA[4]*u4;
            opA[v] = make_float2(rA, rB);
        }
        if (vb) {
            float rA = zB[0]*w0.x + zB[1]*w0.y + zB[2]*w0.z + zB[3]*w0.w + zB[4]*w4;
            float rB = zB[0]*u0.x + zB[1]*u0.y + zB[2]*u0.z + zB[3]*u0.w + zB[4]*u4;
            opB[v] = make_float2(rA, rB);
        }
    }
}

extern "C" void kernel_launch(void* const* d_in, const int* in_sizes, int n_in,
                              void* d_out, int out_size, void* d_ws, size_t ws_size,
                              hipStream_t stream) {
    const int N = in_sizes[0]; // B*T
    if (ws_size >= WS_NEED && d_ws != nullptr) {
        setup_kernel<<<8, 64, 0, stream>>>(
            (const float*)d_in[1], (const float*)d_in[2], (const float*)d_in[3],
            (const float*)d_in[4], (const float*)d_in[5], (const float*)d_in[6],
            (const float*)d_in[7], (const float*)d_in[8], (const float*)d_in[9],
            (const float*)d_in[10], (const float*)d_in[11], (const float*)d_in[12],
            (const float*)d_in[13], (const float*)d_in[14], (const float*)d_in[15],
            (const float*)d_in[16], (const float*)d_in[17], (const float*)d_in[18],
            (const float*)d_in[19], (const float*)d_in[20], (const float*)d_in[21],
            (const float*)d_in[22],
            (float4*)d_ws);
        const int grid = (N + NEL - 1) / NEL;
        micro_main<<<grid, BLK, 0, stream>>>(
            (const int*)d_in[0], (const float4*)d_ws, (float*)d_out, N);
    } else {
        const int grid = (N + L_NEL - 1) / L_NEL;
        micro_fused_legacy<<<grid, L_BLK, 0, stream>>>(
            (const int*)d_in[0],
            (const float*)d_in[1], (const float*)d_in[2], (const float*)d_in[3],
            (const float*)d_in[4], (const float*)d_in[5], (const float*)d_in[6],
            (const float*)d_in[7], (const float*)d_in[8], (const float*)d_in[9],
            (const float*)d_in[10], (const float*)d_in[11], (const float*)d_in[12],
            (const float*)d_in[13], (const float*)d_in[14], (const float*)d_in[15],
            (const float*)d_in[16], (const float*)d_in[17], (const float*)d_in[18],
            (const float*)d_in[19], (const float*)d_in[20], (const float*)d_in[21],
            (const float*)d_in[22],
            (float*)d_out, N);
    }
}

// Round 9
// 214.388 us; speedup vs baseline: 1.1406x; 1.1406x over previous
//
#include <hip/hip_runtime.h>
#include <math.h>

#define T_SEQ 34
#define NTOK 14
#define NE (T_SEQ * NTOK) // 476
#define ROWS 15           // rows per block
#define BLK 512
#define NEL (ROWS * T_SEQ) // 510 elements per block
#define TTS 17            // toksT row stride: banks (17s+r)%32 -> conflict-free both phases

// Single-phase kernel: per-block tables, one barrier, t-major element mapping
// (thread ii -> t = ii/15, r = ii%15). Waves get near-uniform loop bounds
// (within-wave t spread <= 5), short-t waves retire early. No Av redistribution,
// no workspace, epilogue + store inline per thread.
__global__ __launch_bounds__(BLK) void micro_fused_kernel(
    const int* __restrict__ idx,
    const float* __restrict__ tok_emb,
    const float* __restrict__ s_amp, const float* __restrict__ s_phase,
    const float* __restrict__ s_slope, const float* __restrict__ s_offset,
    const float* __restrict__ pc_slope, const float* __restrict__ pc_int,
    const float* __restrict__ z_hi, const float* __restrict__ spec,
    const float* __restrict__ q_w, const float* __restrict__ v_w,
    const float* __restrict__ out_A, const float* __restrict__ out_B,
    const float* __restrict__ q_phase,
    const float* __restrict__ ln1_w, const float* __restrict__ ln2_w,
    const float* __restrict__ lnf_w,
    const float* __restrict__ fc1_w, const float* __restrict__ fc1_b,
    const float* __restrict__ fc2_w, const float* __restrict__ fc2_b,
    const float* __restrict__ head_w,
    float* __restrict__ out, int N)
{
    __shared__ float4 H4[NE];      // (h2,h3,h4,h0) RMS-normed
    __shared__ float  H1f[NE];     // h1
    __shared__ float4 C3[NE];      // q_w^T @ q_rot * invsqrt(5) * log2(e)
    __shared__ int    toksT[T_SEQ * TTS];
    alignas(16) __shared__ float PosT[T_SEQ * 3];
    alignas(16) __shared__ float TE[NTOK * 2];
    alignas(16) __shared__ float PMs[12];
    alignas(16) __shared__ float WsT[NTOK * 8];
    alignas(16) __shared__ float ln2s[8], lnfs[8], fc1ws[12], fc2ws[12], fc2bs[8];
    __shared__ float fc1bs[2];

    const int tid = threadIdx.x;
    const int elemBase = blockIdx.x * NEL;

    // ---- stage tokens (coalesced read, transposed store; stride 17 kills the
    //      16-way write conflict a stride-16 layout would have) ----
    if (tid < NEL) {
        int g = elemBase + tid;
        int v = (g < N) ? idx[g] : 0;
        int r = tid / T_SEQ, s = tid - r * T_SEQ;
        toksT[s * TTS + r] = v;
    }

    // ---- build per-(t,tok) tables (R3-proven math) ----
    if (tid < NE) {
        const float amp = s_amp[0], ph = s_phase[0], slp = s_slope[0], off = s_offset[0];
        const float pcs = pc_slope[0], pci = pc_int[0];
        const float cph = cosf(q_phase[0]), sph = sinf(q_phase[0]);
        const float cscale = 0.44721359549995793f * 1.4426950408889634f; // 1/sqrt(5)*log2e
        const int e = tid;
        const int t = e / NTOK, tk = e - t * NTOK;
        float px, py, pz;
        if (t == 33)      { px = 0.f;     py = 0.f;     pz = 0.f; }
        else if (t == 32) { px = z_hi[0]; py = z_hi[1]; pz = z_hi[2]; }
        else if (t == 10) { px = spec[0]; py = spec[1]; pz = spec[2]; }
        else if (t == 21) { px = spec[3]; py = spec[4]; pz = spec[5]; }
        else {
            int i = (t < 10) ? t : (t < 21 ? t - 11 : t - 22);
            float fi = (float)i;
            float ang = 0.62831853071795864769f * fi + ph;
            float mlt = 1.f + pci + pcs * fi;
            px = amp * cosf(ang) * mlt;
            py = amp * sinf(ang) * mlt;
            pz = (slp * fi + off) * mlt;
        }
        if (tk == 0) { PosT[t*3] = px; PosT[t*3+1] = py; PosT[t*3+2] = pz; }
        float x0 = tok_emb[tk * 2], x1 = tok_emb[tk * 2 + 1];
        float ssum = x0*x0 + x1*x1 + px*px + py*py + pz*pz;
        float rn = rsqrtf(ssum * 0.2f + 1e-5f);
        float h0 = x0 * rn * ln1_w[0], h1 = x1 * rn * ln1_w[1];
        float h2 = px * rn * ln1_w[2], h3 = py * rn * ln1_w[3], h4 = pz * rn * ln1_w[4];
        float q0 = q_w[0]  * h2 + q_w[1]  * h3 + q_w[2]  * h4;
        float q1 = q_w[3]  * h2 + q_w[4]  * h3 + q_w[5]  * h4;
        float q2 = q_w[6]  * h2 + q_w[7]  * h3 + q_w[8]  * h4;
        float q3 = q_w[9]  * h2 + q_w[10] * h3 + q_w[11] * h4;
        float q4 = q_w[12] * h2 + q_w[13] * h3 + q_w[14] * h4;
        float r0 = q0 * cph - q1 * sph, r1 = q0 * sph + q1 * cph;
        float r2c = q2 * cph - q3 * sph, r3 = q2 * sph + q3 * cph;
        float c0 = (r0*q_w[0] + r1*q_w[3] + r2c*q_w[6] + r3*q_w[9]  + q4*q_w[12]) * cscale;
        float c1 = (r0*q_w[1] + r1*q_w[4] + r2c*q_w[7] + r3*q_w[10] + q4*q_w[13]) * cscale;
        float c2 = (r0*q_w[2] + r1*q_w[5] + r2c*q_w[8] + r3*q_w[11] + q4*q_w[14]) * cscale;
        H4[e] = make_float4(h2, h3, h4, h0);
        H1f[e] = h1;
        C3[e] = make_float4(c0, c1, c2, 0.f);
    }
    if (tid < 28) TE[tid] = tok_emb[tid];
    if (tid < 70) { // WsT[v][d] = sum_c head_w[c*5+d] * tok_emb[v*2+c]
        int v = tid / 5, d = tid - v * 5;
        WsT[v * 8 + d] = head_w[d] * tok_emb[v * 2] + head_w[5 + d] * tok_emb[v * 2 + 1];
    }
    if (tid < 10) { // PM[j][c] = sum_i (out_A@out_B)[i][j] * v_w[i*2+c]
        int j = tid >> 1, c = tid & 1;
        float acc = 0.f;
        for (int i = 0; i < 5; ++i) {
            float m5 = out_A[i*2] * out_B[j] + out_A[i*2+1] * out_B[5 + j];
            acc += m5 * v_w[i*2 + c];
        }
        PMs[tid] = acc;
    }
    if (tid < 5)  { ln2s[tid] = ln2_w[tid]; lnfs[tid] = lnf_w[tid]; fc2bs[tid] = fc2_b[tid]; }
    if (tid < 10) { fc1ws[tid] = fc1_w[tid]; fc2ws[tid] = fc2_w[tid]; }
    if (tid < 2)  { fc1bs[tid] = fc1_b[tid]; }

    __syncthreads();

    // ---- t-major element mapping: waves carry near-uniform loop bounds ----
    if (tid >= NEL) return;
    const int t = tid / ROWS;          // 0..33
    const int r = tid - t * ROWS;      // 0..14
    const int lin = elemBase + r * T_SEQ + t;

    // attention for own element (divergent bound; <=5 iter spread per wave)
    const int tokt = toksT[t * TTS + r];
    const float4 c3 = C3[t * NTOK + tokt];
    float l = 0.f, a0 = 0.f, a1 = 0.f;
#pragma unroll 4
    for (int s = 0; s <= t; ++s) {
        int tok = toksT[s * TTS + r];      // lanes same s: <=15 words, conflict-free
        int e = s * NTOK + tok;
        float4 h = H4[e];                  // 2-way worst (e vs e+8) = free
        float h1v = H1f[e];
        float sc = fmaf(c3.x, h.x, fmaf(c3.y, h.y, c3.z * h.z));
        float p = __builtin_amdgcn_exp2f(sc);
        l += p;
        a0 = fmaf(p, h.w, a0);
        a1 = fmaf(p, h1v, a1);
    }
    const float il = __builtin_amdgcn_rcpf(l);
    a0 *= il; a1 *= il;

    if (lin >= N) return;

    // ---- epilogue inline (no redistribution, no extra barrier) ----
    const float xv0 = TE[tokt * 2], xv1 = TE[tokt * 2 + 1];
    const float xv2 = PosT[t*3], xv3 = PosT[t*3+1], xv4 = PosT[t*3+2];

    float y[5];
    y[0] = xv0 + PMs[0] * a0 + PMs[1] * a1;
    y[1] = xv1 + PMs[2] * a0 + PMs[3] * a1;
    y[2] = xv2 + PMs[4] * a0 + PMs[5] * a1;
    y[3] = xv3 + PMs[6] * a0 + PMs[7] * a1;
    y[4] = xv4 + PMs[8] * a0 + PMs[9] * a1;

    float s2 = y[0]*y[0] + y[1]*y[1] + y[2]*y[2] + y[3]*y[3] + y[4]*y[4];
    float r2 = rsqrtf(s2 * 0.2f + 1e-5f);
    float hh[5];
#pragma unroll
    for (int j = 0; j < 5; ++j) hh[j] = y[j] * r2 * ln2s[j];

    float u0 = fc1bs[0], u1 = fc1bs[1];
#pragma unroll
    for (int j = 0; j < 5; ++j) { u0 += hh[j] * fc1ws[j]; u1 += hh[j] * fc1ws[5 + j]; }
    float g0 = 0.5f * u0 * (1.f + erff(u0 * 0.70710678118654752f));
    float g1v = 0.5f * u1 * (1.f + erff(u1 * 0.70710678118654752f));

    float y2[5]; float s3 = 0.f;
#pragma unroll
    for (int j = 0; j < 5; ++j) {
        y2[j] = y[j] + g0 * fc2ws[j * 2] + g1v * fc2ws[j * 2 + 1] + fc2bs[j];
        s3 += y2[j] * y2[j];
    }
    float r3 = rsqrtf(s3 * 0.2f + 1e-5f);
    float z[5];
#pragma unroll
    for (int j = 0; j < 5; ++j) z[j] = y2[j] * r3 * lnfs[j];

    float2* op = (float2*)(out + (size_t)lin * 14);
#pragma unroll
    for (int v = 0; v < 7; ++v) {
        float4 w0 = *(const float4*)&WsT[(2*v) * 8];
        float  w4 = WsT[(2*v) * 8 + 4];
        float4 u0v = *(const float4*)&WsT[(2*v+1) * 8];
        float  u4 = WsT[(2*v+1) * 8 + 4];
        float rA = z[0]*w0.x + z[1]*w0.y + z[2]*w0.z + z[3]*w0.w + z[4]*w4;
        float rB = z[0]*u0v.x + z[1]*u0v.y + z[2]*u0v.z + z[3]*u0v.w + z[4]*u4;
        op[v] = make_float2(rA, rB);
    }
}

extern "C" void kernel_launch(void* const* d_in, const int* in_sizes, int n_in,
                              void* d_out, int out_size, void* d_ws, size_t ws_size,
                              hipStream_t stream) {
    const int N = in_sizes[0]; // B*T
    const int grid = (N + NEL - 1) / NEL;
    micro_fused_kernel<<<grid, BLK, 0, stream>>>(
        (const int*)d_in[0],
        (const float*)d_in[1], (const float*)d_in[2], (const float*)d_in[3],
        (const float*)d_in[4], (const float*)d_in[5], (const float*)d_in[6],
        (const float*)d_in[7], (const float*)d_in[8], (const float*)d_in[9],
        (const float*)d_in[10], (const float*)d_in[11], (const float*)d_in[12],
        (const float*)d_in[13], (const float*)d_in[14], (const float*)d_in[15],
        (const float*)d_in[16], (const float*)d_in[17], (const float*)d_in[18],
        (const float*)d_in[19], (const float*)d_in[20], (const float*)d_in[21],
        (const float*)d_in[22],
        (float*)d_out, N);
}